// Round 11
// baseline (142.737 us; speedup 1.0000x reference)
//
#include <hip/hip_runtime.h>

#define KNN 20
#define EPSBN 1e-5f

__device__ __forceinline__ float lrelu(float z) { return fmaxf(z, 0.2f * z); }

__device__ __forceinline__ int mbcnt64(unsigned long long m) {
  return __builtin_amdgcn_mbcnt_hi((unsigned)(m >> 32),
                                   __builtin_amdgcn_mbcnt_lo((unsigned)m, 0));
}

// Full-wave (64-lane) float sum via DPP (VALU pipe, no LDS). Proven R2-R10.
__device__ __forceinline__ float wave64_sum(float x) {
#define DPP_ADD(ctrl)                                                                   \
  {                                                                                     \
    int _t = __builtin_amdgcn_update_dpp(0, __float_as_int(x), (ctrl), 0xF, 0xF, true); \
    x += __int_as_float(_t);                                                            \
  }
  DPP_ADD(0x111)  // row_shr:1
  DPP_ADD(0x112)  // row_shr:2
  DPP_ADD(0x114)  // row_shr:4
  DPP_ADD(0x118)  // row_shr:8
  DPP_ADD(0x142)  // row_bcast15
  DPP_ADD(0x143)  // row_bcast31 -> lane63 = total
#undef DPP_ADD
  return __int_as_float(__builtin_amdgcn_readlane(__float_as_int(x), 63));
}

// One bitonic stage on 32-bit keys. Exchange: stride 1,2 via quad_perm DPP (VALU,
// ~5cyc, R9-proven patterns); stride 4,8,16 via ds_swizzle; 32 via ds_bpermute.
// Instruction count identical to the all-LDS R10 version; chain latency lower.
template <int LK, int LJ>
__device__ __forceinline__ void bstage(unsigned& x, const int* db, int addr32) {
  unsigned p;
  if constexpr (LJ == 0)
    p = (unsigned)__builtin_amdgcn_update_dpp((int)x, (int)x, 0xB1, 0xF, 0xF, false);  // quad_perm [1,0,3,2]
  else if constexpr (LJ == 1)
    p = (unsigned)__builtin_amdgcn_update_dpp((int)x, (int)x, 0x4E, 0xF, 0xF, false);  // quad_perm [2,3,0,1]
  else if constexpr (LJ == 5)
    p = (unsigned)__builtin_amdgcn_ds_bpermute(addr32, (int)x);
  else
    p = (unsigned)__builtin_amdgcn_ds_swizzle((int)x, ((1 << LJ) << 10) | 0x1F);
  const unsigned mn = min(x, p), mx = max(x, p);
  x = ((db[LK] ^ db[LJ]) == 0) ? mn : mx;
}

__device__ __forceinline__ unsigned bsort64(unsigned x, const int* db, int addr32) {
  bstage<1, 0>(x, db, addr32);
  bstage<2, 1>(x, db, addr32); bstage<2, 0>(x, db, addr32);
  bstage<3, 2>(x, db, addr32); bstage<3, 1>(x, db, addr32); bstage<3, 0>(x, db, addr32);
  bstage<4, 3>(x, db, addr32); bstage<4, 2>(x, db, addr32); bstage<4, 1>(x, db, addr32);
  bstage<4, 0>(x, db, addr32);
  bstage<5, 4>(x, db, addr32); bstage<5, 3>(x, db, addr32); bstage<5, 2>(x, db, addr32);
  bstage<5, 1>(x, db, addr32); bstage<5, 0>(x, db, addr32);
  bstage<6, 5>(x, db, addr32); bstage<6, 4>(x, db, addr32); bstage<6, 3>(x, db, addr32);
  bstage<6, 2>(x, db, addr32); bstage<6, 1>(x, db, addr32); bstage<6, 0>(x, db, addr32);
  return x;
}

// Bitonic stage on (key<<32|index) pairs: 2 exchanges (hi,lo) + v_cmp_lt_u64 +
// cndmask pair via (lt == up) ? x : p. Stride 1,2 on DPP; rest on LDS pipe.
template <int LK, int LJ>
__device__ __forceinline__ void bstage64(unsigned long long& x, const int* db, int addr32) {
  const unsigned lo = (unsigned)x, hi = (unsigned)(x >> 32);
  unsigned plo, phi;
  if constexpr (LJ == 0) {
    plo = (unsigned)__builtin_amdgcn_update_dpp((int)lo, (int)lo, 0xB1, 0xF, 0xF, false);
    phi = (unsigned)__builtin_amdgcn_update_dpp((int)hi, (int)hi, 0xB1, 0xF, 0xF, false);
  } else if constexpr (LJ == 1) {
    plo = (unsigned)__builtin_amdgcn_update_dpp((int)lo, (int)lo, 0x4E, 0xF, 0xF, false);
    phi = (unsigned)__builtin_amdgcn_update_dpp((int)hi, (int)hi, 0x4E, 0xF, 0xF, false);
  } else if constexpr (LJ == 5) {
    plo = (unsigned)__builtin_amdgcn_ds_bpermute(addr32, (int)lo);
    phi = (unsigned)__builtin_amdgcn_ds_bpermute(addr32, (int)hi);
  } else {
    plo = (unsigned)__builtin_amdgcn_ds_swizzle((int)lo, ((1 << LJ) << 10) | 0x1F);
    phi = (unsigned)__builtin_amdgcn_ds_swizzle((int)hi, ((1 << LJ) << 10) | 0x1F);
  }
  const unsigned long long p = ((unsigned long long)phi << 32) | plo;
  const bool up = ((db[LK] ^ db[LJ]) == 0);
  const bool lt = x < p;
  x = (lt == up) ? x : p;
}

__device__ __forceinline__ unsigned long long bsort64p(unsigned long long x, const int* db,
                                                       int addr32) {
  bstage64<1, 0>(x, db, addr32);
  bstage64<2, 1>(x, db, addr32); bstage64<2, 0>(x, db, addr32);
  bstage64<3, 2>(x, db, addr32); bstage64<3, 1>(x, db, addr32); bstage64<3, 0>(x, db, addr32);
  bstage64<4, 3>(x, db, addr32); bstage64<4, 2>(x, db, addr32); bstage64<4, 1>(x, db, addr32);
  bstage64<4, 0>(x, db, addr32);
  bstage64<5, 4>(x, db, addr32); bstage64<5, 3>(x, db, addr32); bstage64<5, 2>(x, db, addr32);
  bstage64<5, 1>(x, db, addr32); bstage64<5, 0>(x, db, addr32);
  bstage64<6, 5>(x, db, addr32); bstage64<6, 4>(x, db, addr32); bstage64<6, 3>(x, db, addr32);
  bstage64<6, 2>(x, db, addr32); bstage64<6, 1>(x, db, addr32); bstage64<6, 0>(x, db, addr32);
  return x;
}

// ---------------- K0: pack points + fold BN/LAB weights (byte-identical to R7-R10) ----------------
__global__ __launch_bounds__(256) void prep_kernel(const float* __restrict__ x,
                                                   float4* __restrict__ xq,
                                                   const float* __restrict__ Wk,
                                                   const float* __restrict__ Wv,
                                                   const float* __restrict__ Ws,
                                                   const float* __restrict__ bnk,
                                                   const float* __restrict__ bnv,
                                                   const float* __restrict__ bns,
                                                   float* __restrict__ wf) {
  if (blockIdx.x == 256) {
    const int c = threadIdx.x;
    if (c < 64) {
      const float sk = bnk[c] / sqrtf(bnk[192 + c] + EPSBN);
      const float hk = bnk[64 + c] - bnk[128 + c] * sk;
      const float sv = bnv[c] / sqrtf(bnv[192 + c] + EPSBN);
      const float hv = bnv[64 + c] - bnv[128 + c] * sv;
      const float ss = bns[0] / sqrtf(bns[3] + EPSBN);
      float* r = wf + (c << 4);
      r[0] = Wk[c * 3 + 0] * sk; r[1] = Wk[c * 3 + 1] * sk; r[2] = Wk[c * 3 + 2] * sk;
      r[3] = hk;
      r[4] = Wv[c * 10 + 0] * sv;
      r[5] = (Wv[c * 10 + 1] + Wv[c * 10 + 7]) * sv;
      r[6] = (Wv[c * 10 + 2] + Wv[c * 10 + 8]) * sv;
      r[7] = (Wv[c * 10 + 3] + Wv[c * 10 + 9]) * sv;
      r[8] = (Wv[c * 10 + 4] + Wv[c * 10 + 7]) * sv;
      r[9] = (Wv[c * 10 + 5] + Wv[c * 10 + 8]) * sv;
      r[10] = (Wv[c * 10 + 6] + Wv[c * 10 + 9]) * sv;
      r[11] = hv;
      r[12] = Ws[c] * ss;
      if (c == 0) wf[1024] = bns[1] - bns[2] * ss;  // hs
    }
    return;
  }
  const int t = blockIdx.x * 256 + threadIdx.x;  // t = b*1024 + n
  const int b = t >> 10, n = t & 1023;
  const float* xb = x + b * 3072;
  const float x0 = xb[n], x1 = xb[1024 + n], x2 = xb[2048 + n];
  float4 p;
  p.x = x0; p.y = x1; p.z = x2;
  p.w = x0 * x0 + x1 * x1 + x2 * x2;
  xq[t] = p;
}

// ---------------- K1: FUSED kNN + LAB attention (one wave per point) ----------------
// Selection/lab identical in semantics+arithmetic to R10. LDS change: comp (phase B)
// now ALIASES the tld tile (phase C) -- both wave-private, used in disjoint phases of
// the same wave (program-ordered, no barrier needed). LDS/block 23552 -> 21504 B ->
// 7 blocks/CU instead of 6.
__global__ __launch_bounds__(256) void point_kernel(const float4* __restrict__ xq,
                                                    const float* __restrict__ wf,
                                                    float* __restrict__ agg_out) {
  __shared__ float tld[4][64][21];
  const int lane = threadIdx.x & 63;
  const int w = threadIdx.x >> 6;
  const int point = __builtin_amdgcn_readfirstlane(blockIdx.x * 4 + w);  // wave-uniform
  const int b = point >> 10;
  const int iself = point & 1023;
  const float4* xb = xq + (b << 10);

  // Lab weights issued early: VMEM latency hides under the distance phase.
  const int c = lane;
  const float4* wfc = (const float4*)(wf + (c << 4));
  const float4 w0 = wfc[0];   // wk0,wk1,wk2,hk
  const float4 w1 = wfc[1];   // wv_ded, wd0, wd1, wd2
  const float4 w2 = wfc[2];   // wc0, wc1, wc2, hv
  const float wss = wf[(c << 4) + 12];
  const float hs = wf[1024];
  const float4 ci = xq[point];                         // uniform -> s_load

  // ---- phase A: distances (bit-identical to R2-R10) ----
  unsigned u[16];
#pragma unroll
  for (int r = 0; r < 16; ++r) {
    const int j = (r << 6) + lane;
    const float4 p = xb[j];
    const float dot = ci.x * p.x + ci.y * p.y + ci.z * p.z;
    const float pd = 2.0f * dot - ci.w - p.w;
    const unsigned ub = __float_as_uint(pd) ^ 0x80000000u;
    u[r] = (j == iself) ? 0u : ub;
  }

  int db[7];
#pragma unroll
  for (int a = 0; a < 6; ++a) db[a] = (lane >> a) & 1;
  db[6] = 0;
  const int addr32 = (lane ^ 32) << 2;

  unsigned lm = u[0];
#pragma unroll
  for (int r = 1; r < 16; ++r) lm = min(lm, u[r]);

  const unsigned sm = bsort64(lm, db, addr32);
  const unsigned tau = (unsigned)__builtin_amdgcn_readlane((int)sm, 19);

  // Compact survivor PAIRS (u <= tau) into this wave's LDS slots (aliases tld[w],
  // which is not live until phase C).
  unsigned long long* cw = (unsigned long long*)&tld[w][0][0];
  cw[lane] = ~0ull;                                // pad sorts to the end
  int base = 0;
#pragma unroll
  for (int r = 0; r < 16; ++r) {
    const bool sel = (u[r] <= tau);
    const unsigned long long m = __ballot(sel);
    const int pos = base + mbcnt64(m);
    if (sel && pos < 64)
      cw[pos] = ((unsigned long long)u[r] << 32) | (unsigned)((r << 6) + lane);
    base += __popcll(m);
  }
  unsigned long long svp = cw[lane];

  int jwin;
  if (base <= 64) {                                // always, in practice
    svp = bsort64p(svp, db, addr32);
    jwin = (int)(unsigned)svp;                     // lane r = r-th nearest (r < 20 used)
  } else {
    // Fallback: proven R3 bisection for exact T + R8 two-pass collection.
    unsigned T = 0u;
    for (int bit = 30; bit >= 0; --bit) {
      const unsigned cand = T | (1u << bit);
      int cnt = 0;
#pragma unroll
      for (int r = 0; r < 16; ++r) cnt += __popcll(__ballot(u[r] < cand));
      if (cnt <= 19) T = cand;
    }
    unsigned* cw32 = (unsigned*)cw;
    int nbase = 0;
#pragma unroll
    for (int r = 0; r < 16; ++r) {
      const bool sel = (u[r] < T);
      const unsigned long long m = __ballot(sel);
      const int pos = nbase + mbcnt64(m);
      if (sel) cw32[pos] = (unsigned)((r << 6) + lane);
      nbase += __popcll(m);
    }
    for (int r = 0; r < 16 && nbase < KNN; ++r) {
      const bool sel = (u[r] == T);
      const unsigned long long m = __ballot(sel);
      const int pos = nbase + mbcnt64(m);
      if (sel && pos < KNN) cw32[pos] = (unsigned)((r << 6) + lane);
      nbase += __popcll(m);
    }
    jwin = (int)cw32[lane];
  }

  // ---- phase C: LAB attention (R8/R10-proven math + tld transpose reduction) ----
  const float q = lrelu(fmaf(w0.x, ci.x, fmaf(w0.y, ci.y, fmaf(w0.z, ci.z, w0.w))));
  const float cterm = fmaf(w2.x, ci.x, fmaf(w2.y, ci.y, fmaf(w2.z, ci.z, w2.w)));
  const float sbase = wave64_sum(wss * q) + hs;

  float v[KNN];
#pragma unroll
  for (int k = 0; k < KNN; ++k) {
    const int jk = __builtin_amdgcn_readlane(jwin, k);   // SGPR -> uniform gather
    const float4 nb = xb[jk];
    const float d0 = nb.x - ci.x, d1 = nb.y - ci.y, d2 = nb.z - ci.z;
    const float ded = fmaf(d0, d0, fmaf(d1, d1, d2 * d2));
    const float z = fmaf(w1.x, ded, fmaf(w1.y, d0, fmaf(w1.z, d1, fmaf(w1.w, d2, cterm))));
    v[k] = lrelu(z);
  }

  // Transpose reduction over channels via wave-private LDS tile (R7-R10-proven).
  // (comp's lifetime ended at the ds_read of svp above; same-wave LDS ops are ordered.)
  float* trow = &tld[w][c][0];
#pragma unroll
  for (int k = 0; k < KNN; ++k) trow[k] = wss * v[k];
  const int g = lane / 20;                       // 3 for lanes 60..63 (unused results)
  const int kk = lane - g * 20;
  const int c0 = (g == 0) ? 0 : ((g == 1) ? 22 : 43);
  const int cnt = (g == 0) ? 22 : 21;
  float part = 0.f;
#pragma unroll
  for (int i = 0; i < 22; ++i)
    if (i < cnt) part += tld[w][c0 + i][kk];
  const float p1 = __int_as_float(
      __builtin_amdgcn_ds_bpermute((kk + 20) << 2, __float_as_int(part)));
  const float p2 = __int_as_float(
      __builtin_amdgcn_ds_bpermute((kk + 40) << 2, __float_as_int(part)));
  const float sfull = lrelu(part + p1 + p2 + sbase);  // valid in lanes 0..19

  float sk_[KNN];
#pragma unroll
  for (int k = 0; k < KNN; ++k)
    sk_[k] = __int_as_float(__builtin_amdgcn_readlane(__float_as_int(sfull), k));

  float m = sk_[0];
#pragma unroll
  for (int k = 1; k < KNN; ++k) m = fmaxf(m, sk_[k]);
  const float nm = -m * 1.44269504f;
  float den = 0.f, agg = 0.f;
#pragma unroll
  for (int k = 0; k < KNN; ++k) {
    const float e = exp2f(fmaf(sk_[k], 1.44269504f, nm));
    den += e;
    agg = fmaf(v[k], e, agg);
  }
  agg_out[(point << 6) + c] = agg * (1.0f / den);  // [point][c] -> coalesced
}

// ---------------- K3: conv2 (64x64) + BN + ReLU (byte-identical, proven) ----------------
__global__ __launch_bounds__(256) void conv2_kernel(const float* __restrict__ agg,
                                                    const float* __restrict__ W2,
                                                    const float* __restrict__ b2,
                                                    const float* __restrict__ bnc2,
                                                    float* __restrict__ out) {
  const int t = blockIdx.x * 256 + threadIdx.x;  // t = b*1024 + n
  const float4* a4 = (const float4*)(agg + (t << 6));
  float acc[64];
#pragma unroll
  for (int o = 0; o < 64; ++o) acc[o] = 0.f;
#pragma unroll
  for (int cq = 0; cq < 16; ++cq) {
    const float4 a = a4[cq];
#pragma unroll
    for (int o = 0; o < 64; ++o) {
      const float* w = W2 + (o << 6) + (cq << 2);
      acc[o] = fmaf(w[0], a.x, fmaf(w[1], a.y, fmaf(w[2], a.z, fmaf(w[3], a.w, acc[o]))));
    }
  }
  const int b = t >> 10, n = t & 1023;
  float* op = out + (b << 16) + n;
#pragma unroll
  for (int o = 0; o < 64; ++o) {
    const float sc = bnc2[o] / sqrtf(bnc2[192 + o] + EPSBN);
    const float z = acc[o] + b2[o];
    op[o << 10] = fmaxf(fmaf(z - bnc2[128 + o], sc, bnc2[64 + o]), 0.f);
  }
}

extern "C" void kernel_launch(void* const* d_in, const int* in_sizes, int n_in,
                              void* d_out, int out_size, void* d_ws, size_t ws_size,
                              hipStream_t stream) {
  const float* x    = (const float*)d_in[0];
  const float* Wk   = (const float*)d_in[1];
  const float* Wv   = (const float*)d_in[2];
  const float* Ws   = (const float*)d_in[3];
  const float* W2   = (const float*)d_in[4];
  const float* b2   = (const float*)d_in[5];
  const float* bnk  = (const float*)d_in[6];
  const float* bnv  = (const float*)d_in[7];
  const float* bns  = (const float*)d_in[8];
  const float* bnc2 = (const float*)d_in[9];

  // ws layout: xq (1 MB) | agg (16 MB)
  float4* xq = (float4*)d_ws;
  float* agg = (float*)((char*)d_ws + 6291456);
  float* out = (float*)d_out;
  // Folded-weight scratch (4.1 KB) at the START of d_out: point_kernel reads it, then
  // conv2 overwrites every element of d_out (stream-serialized) -> race-free.
  float* wf = (float*)d_out;

  prep_kernel<<<257, 256, 0, stream>>>(x, xq, Wk, Wv, Ws, bnk, bnv, bns, wf);
  point_kernel<<<16384, 256, 0, stream>>>(xq, wf, agg);
  conv2_kernel<<<256, 256, 0, stream>>>(agg, W2, b2, bnc2, out);
}

// Round 12
// 130.067 us; speedup vs baseline: 1.0974x; 1.0974x over previous
//
#include <hip/hip_runtime.h>

#define KNN 20
#define EPSBN 1e-5f

__device__ __forceinline__ float lrelu(float z) { return fmaxf(z, 0.2f * z); }

__device__ __forceinline__ int mbcnt64(unsigned long long m) {
  return __builtin_amdgcn_mbcnt_hi((unsigned)(m >> 32),
                                   __builtin_amdgcn_mbcnt_lo((unsigned)m, 0));
}

// Full-wave (64-lane) float sum via DPP (VALU pipe, no LDS). Proven R2-R11.
__device__ __forceinline__ float wave64_sum(float x) {
#define DPP_ADD(ctrl)                                                                   \
  {                                                                                     \
    int _t = __builtin_amdgcn_update_dpp(0, __float_as_int(x), (ctrl), 0xF, 0xF, true); \
    x += __int_as_float(_t);                                                            \
  }
  DPP_ADD(0x111)  // row_shr:1
  DPP_ADD(0x112)  // row_shr:2
  DPP_ADD(0x114)  // row_shr:4
  DPP_ADD(0x118)  // row_shr:8
  DPP_ADD(0x142)  // row_bcast15
  DPP_ADD(0x143)  // row_bcast31 -> lane63 = total
#undef DPP_ADD
  return __int_as_float(__builtin_amdgcn_readlane(__float_as_int(x), 63));
}

// One bitonic stage on 32-bit keys (R10-proven all-LDS form: ds_swizzle/bpermute
// exchange on the LDS pipe -- keeps the saturated VALU pipe free).
template <int LK, int LJ>
__device__ __forceinline__ void bstage(unsigned& x, const int* db, int addr32) {
  unsigned p;
  if constexpr (LJ == 5)
    p = (unsigned)__builtin_amdgcn_ds_bpermute(addr32, (int)x);
  else
    p = (unsigned)__builtin_amdgcn_ds_swizzle((int)x, ((1 << LJ) << 10) | 0x1F);
  const unsigned mn = min(x, p), mx = max(x, p);
  x = ((db[LK] ^ db[LJ]) == 0) ? mn : mx;
}

__device__ __forceinline__ unsigned bsort64(unsigned x, const int* db, int addr32) {
  bstage<1, 0>(x, db, addr32);
  bstage<2, 1>(x, db, addr32); bstage<2, 0>(x, db, addr32);
  bstage<3, 2>(x, db, addr32); bstage<3, 1>(x, db, addr32); bstage<3, 0>(x, db, addr32);
  bstage<4, 3>(x, db, addr32); bstage<4, 2>(x, db, addr32); bstage<4, 1>(x, db, addr32);
  bstage<4, 0>(x, db, addr32);
  bstage<5, 4>(x, db, addr32); bstage<5, 3>(x, db, addr32); bstage<5, 2>(x, db, addr32);
  bstage<5, 1>(x, db, addr32); bstage<5, 0>(x, db, addr32);
  bstage<6, 5>(x, db, addr32); bstage<6, 4>(x, db, addr32); bstage<6, 3>(x, db, addr32);
  bstage<6, 2>(x, db, addr32); bstage<6, 1>(x, db, addr32); bstage<6, 0>(x, db, addr32);
  return x;
}

// ---------------- K0: pack points + fold BN/LAB weights (byte-identical to R7-R11) ----------------
__global__ __launch_bounds__(256) void prep_kernel(const float* __restrict__ x,
                                                   float4* __restrict__ xq,
                                                   const float* __restrict__ Wk,
                                                   const float* __restrict__ Wv,
                                                   const float* __restrict__ Ws,
                                                   const float* __restrict__ bnk,
                                                   const float* __restrict__ bnv,
                                                   const float* __restrict__ bns,
                                                   float* __restrict__ wf) {
  if (blockIdx.x == 256) {
    const int c = threadIdx.x;
    if (c < 64) {
      const float sk = bnk[c] / sqrtf(bnk[192 + c] + EPSBN);
      const float hk = bnk[64 + c] - bnk[128 + c] * sk;
      const float sv = bnv[c] / sqrtf(bnv[192 + c] + EPSBN);
      const float hv = bnv[64 + c] - bnv[128 + c] * sv;
      const float ss = bns[0] / sqrtf(bns[3] + EPSBN);
      float* r = wf + (c << 4);
      r[0] = Wk[c * 3 + 0] * sk; r[1] = Wk[c * 3 + 1] * sk; r[2] = Wk[c * 3 + 2] * sk;
      r[3] = hk;
      r[4] = Wv[c * 10 + 0] * sv;
      r[5] = (Wv[c * 10 + 1] + Wv[c * 10 + 7]) * sv;
      r[6] = (Wv[c * 10 + 2] + Wv[c * 10 + 8]) * sv;
      r[7] = (Wv[c * 10 + 3] + Wv[c * 10 + 9]) * sv;
      r[8] = (Wv[c * 10 + 4] + Wv[c * 10 + 7]) * sv;
      r[9] = (Wv[c * 10 + 5] + Wv[c * 10 + 8]) * sv;
      r[10] = (Wv[c * 10 + 6] + Wv[c * 10 + 9]) * sv;
      r[11] = hv;
      r[12] = Ws[c] * ss;
      if (c == 0) wf[1024] = bns[1] - bns[2] * ss;  // hs
    }
    return;
  }
  const int t = blockIdx.x * 256 + threadIdx.x;  // t = b*1024 + n
  const int b = t >> 10, n = t & 1023;
  const float* xb = x + b * 3072;
  const float x0 = xb[n], x1 = xb[1024 + n], x2 = xb[2048 + n];
  float4 p;
  p.x = x0; p.y = x1; p.z = x2;
  p.w = x0 * x0 + x1 * x1 + x2 * x2;
  xq[t] = p;
}

// ---------------- K1: FUSED kNN + LAB attention (one wave per point) ----------------
// Selection: tau from sorted lane-min keys -> compact survivor PAIRS in ascending-j
// order (one per lane) -> sort KEYS only -> T at lane 19 -> ONE ballot partition on
// the per-lane pairs (strict-less in j-order, ties fill to 20 in j-order = top_k
// tie-break). Selected SET identical to R8-R11 (downstream is k-permutation-invariant,
// established R2). comp aliases tld (disjoint phases, wave-private, R11-proven safe).
__global__ __launch_bounds__(256) void point_kernel(const float4* __restrict__ xq,
                                                    const float* __restrict__ wf,
                                                    float* __restrict__ agg_out) {
  __shared__ float tld[4][64][21];
  const int lane = threadIdx.x & 63;
  const int w = threadIdx.x >> 6;
  const int point = __builtin_amdgcn_readfirstlane(blockIdx.x * 4 + w);  // wave-uniform
  const int b = point >> 10;
  const int iself = point & 1023;
  const float4* xb = xq + (b << 10);

  // Lab weights issued early: VMEM latency hides under the distance phase.
  const int c = lane;
  const float4* wfc = (const float4*)(wf + (c << 4));
  const float4 w0 = wfc[0];   // wk0,wk1,wk2,hk
  const float4 w1 = wfc[1];   // wv_ded, wd0, wd1, wd2
  const float4 w2 = wfc[2];   // wc0, wc1, wc2, hv
  const float wss = wf[(c << 4) + 12];
  const float hs = wf[1024];
  const float4 ci = xq[point];                         // uniform -> s_load

  // ---- phase A: distances (bit-identical to R2-R11) ----
  unsigned u[16];
#pragma unroll
  for (int r = 0; r < 16; ++r) {
    const int j = (r << 6) + lane;
    const float4 p = xb[j];
    const float dot = ci.x * p.x + ci.y * p.y + ci.z * p.z;
    const float pd = 2.0f * dot - ci.w - p.w;
    const unsigned ub = __float_as_uint(pd) ^ 0x80000000u;
    u[r] = (j == iself) ? 0u : ub;
  }

  int db[7];
#pragma unroll
  for (int a = 0; a < 6; ++a) db[a] = (lane >> a) & 1;
  db[6] = 0;
  const int addr32 = (lane ^ 32) << 2;

  unsigned lm = u[0];
#pragma unroll
  for (int r = 1; r < 16; ++r) lm = min(lm, u[r]);

  const unsigned sm = bsort64(lm, db, addr32);
  const unsigned tau = (unsigned)__builtin_amdgcn_readlane((int)sm, 19);

  // Compact survivor PAIRS (u <= tau) into LDS slots (aliases tld[w], not live
  // until phase C). Compaction order = ascending j.
  unsigned long long* cw = (unsigned long long*)&tld[w][0][0];
  cw[lane] = ~0ull;                                // pad sorts to the end
  int base = 0;
#pragma unroll
  for (int r = 0; r < 16; ++r) {
    const bool sel = (u[r] <= tau);
    const unsigned long long m = __ballot(sel);
    const int pos = base + mbcnt64(m);
    if (sel && pos < 64)
      cw[pos] = ((unsigned long long)u[r] << 32) | (unsigned)((r << 6) + lane);
    base += __popcll(m);
  }
  const unsigned long long svp = cw[lane];

  int jwin;
  if (base <= 64) {                                // always, in practice
    const unsigned mykey = (unsigned)(svp >> 32);
    const unsigned myidx = (unsigned)svp;
    const unsigned skey = bsort64(mykey, db, addr32);
    const unsigned T = (unsigned)__builtin_amdgcn_readlane((int)skey, 19);
    unsigned* cw32 = (unsigned*)cw;
    // Partition on per-lane pairs: strict-less (lane order = j order), then ties.
    const bool lt = (mykey < T);
    const unsigned long long mlt = __ballot(lt);
    if (lt) cw32[mbcnt64(mlt)] = myidx;
    const int n1 = __popcll(mlt);
    const bool eq = (mykey == T);
    const unsigned long long meq = __ballot(eq);
    const int pose = n1 + mbcnt64(meq);
    if (eq && pose < KNN) cw32[pose] = myidx;
    jwin = (int)cw32[lane];                        // lanes 0..19 hold the top-20 set
  } else {
    // Fallback: proven R3 bisection for exact T + R8 two-pass collection.
    unsigned T = 0u;
    for (int bit = 30; bit >= 0; --bit) {
      const unsigned cand = T | (1u << bit);
      int cnt = 0;
#pragma unroll
      for (int r = 0; r < 16; ++r) cnt += __popcll(__ballot(u[r] < cand));
      if (cnt <= 19) T = cand;
    }
    unsigned* cw32 = (unsigned*)cw;
    int nbase = 0;
#pragma unroll
    for (int r = 0; r < 16; ++r) {
      const bool sel = (u[r] < T);
      const unsigned long long m = __ballot(sel);
      const int pos = nbase + mbcnt64(m);
      if (sel) cw32[pos] = (unsigned)((r << 6) + lane);
      nbase += __popcll(m);
    }
    for (int r = 0; r < 16 && nbase < KNN; ++r) {
      const bool sel = (u[r] == T);
      const unsigned long long m = __ballot(sel);
      const int pos = nbase + mbcnt64(m);
      if (sel && pos < KNN) cw32[pos] = (unsigned)((r << 6) + lane);
      nbase += __popcll(m);
    }
    jwin = (int)cw32[lane];
  }

  // ---- phase C: LAB attention (R8-R11-proven math + tld transpose reduction) ----
  const float q = lrelu(fmaf(w0.x, ci.x, fmaf(w0.y, ci.y, fmaf(w0.z, ci.z, w0.w))));
  const float cterm = fmaf(w2.x, ci.x, fmaf(w2.y, ci.y, fmaf(w2.z, ci.z, w2.w)));
  const float sbase = wave64_sum(wss * q) + hs;

  float v[KNN];
#pragma unroll
  for (int k = 0; k < KNN; ++k) {
    const int jk = __builtin_amdgcn_readlane(jwin, k);   // SGPR -> uniform gather
    const float4 nb = xb[jk];
    const float d0 = nb.x - ci.x, d1 = nb.y - ci.y, d2 = nb.z - ci.z;
    const float ded = fmaf(d0, d0, fmaf(d1, d1, d2 * d2));
    const float z = fmaf(w1.x, ded, fmaf(w1.y, d0, fmaf(w1.z, d1, fmaf(w1.w, d2, cterm))));
    v[k] = lrelu(z);
  }

  // Transpose reduction over channels via wave-private LDS tile (R7-R11-proven).
  // (comp's lifetime ended at the reads above; same-wave LDS ops are ordered.)
  float* trow = &tld[w][c][0];
#pragma unroll
  for (int k = 0; k < KNN; ++k) trow[k] = wss * v[k];
  const int g = lane / 20;                       // 3 for lanes 60..63 (unused results)
  const int kk = lane - g * 20;
  const int c0 = (g == 0) ? 0 : ((g == 1) ? 22 : 43);
  const int cnt = (g == 0) ? 22 : 21;
  float part = 0.f;
#pragma unroll
  for (int i = 0; i < 22; ++i)
    if (i < cnt) part += tld[w][c0 + i][kk];
  const float p1 = __int_as_float(
      __builtin_amdgcn_ds_bpermute((kk + 20) << 2, __float_as_int(part)));
  const float p2 = __int_as_float(
      __builtin_amdgcn_ds_bpermute((kk + 40) << 2, __float_as_int(part)));
  const float sfull = lrelu(part + p1 + p2 + sbase);  // valid in lanes 0..19

  float sk_[KNN];
#pragma unroll
  for (int k = 0; k < KNN; ++k)
    sk_[k] = __int_as_float(__builtin_amdgcn_readlane(__float_as_int(sfull), k));

  float m = sk_[0];
#pragma unroll
  for (int k = 1; k < KNN; ++k) m = fmaxf(m, sk_[k]);
  const float nm = -m * 1.44269504f;
  float den = 0.f, agg = 0.f;
#pragma unroll
  for (int k = 0; k < KNN; ++k) {
    const float e = exp2f(fmaf(sk_[k], 1.44269504f, nm));
    den += e;
    agg = fmaf(v[k], e, agg);
  }
  agg_out[(point << 6) + c] = agg * (1.0f / den);  // [point][c] -> coalesced
}

// ---------------- K3: conv2 (64x64) + BN + ReLU ----------------
// Split each point's 64 outputs across 2 blocks (o-half block-uniform -> W2 stays
// scalar s_load). Grid 512: halves the serial 4096-fma chain, doubles waves/CU.
__global__ __launch_bounds__(256) void conv2_kernel(const float* __restrict__ agg,
                                                    const float* __restrict__ W2,
                                                    const float* __restrict__ b2,
                                                    const float* __restrict__ bnc2,
                                                    float* __restrict__ out) {
  const int o0 = (blockIdx.x & 1) << 5;          // 0 or 32, block-uniform
  const int t = (blockIdx.x >> 1) * 256 + threadIdx.x;  // t = b*1024 + n
  const float4* a4 = (const float4*)(agg + (t << 6));
  float acc[32];
#pragma unroll
  for (int oo = 0; oo < 32; ++oo) acc[oo] = 0.f;
#pragma unroll
  for (int cq = 0; cq < 16; ++cq) {
    const float4 a = a4[cq];
#pragma unroll
    for (int oo = 0; oo < 32; ++oo) {
      const float* w = W2 + ((o0 + oo) << 6) + (cq << 2);  // block-uniform -> s_load
      acc[oo] = fmaf(w[0], a.x, fmaf(w[1], a.y, fmaf(w[2], a.z, fmaf(w[3], a.w, acc[oo]))));
    }
  }
  const int b = t >> 10, n = t & 1023;
  float* op = out + (b << 16) + n;
#pragma unroll
  for (int oo = 0; oo < 32; ++oo) {
    const int o = o0 + oo;
    const float sc = bnc2[o] / sqrtf(bnc2[192 + o] + EPSBN);
    const float z = acc[oo] + b2[o];
    op[o << 10] = fmaxf(fmaf(z - bnc2[128 + o], sc, bnc2[64 + o]), 0.f);
  }
}

extern "C" void kernel_launch(void* const* d_in, const int* in_sizes, int n_in,
                              void* d_out, int out_size, void* d_ws, size_t ws_size,
                              hipStream_t stream) {
  const float* x    = (const float*)d_in[0];
  const float* Wk   = (const float*)d_in[1];
  const float* Wv   = (const float*)d_in[2];
  const float* Ws   = (const float*)d_in[3];
  const float* W2   = (const float*)d_in[4];
  const float* b2   = (const float*)d_in[5];
  const float* bnk  = (const float*)d_in[6];
  const float* bnv  = (const float*)d_in[7];
  const float* bns  = (const float*)d_in[8];
  const float* bnc2 = (const float*)d_in[9];

  // ws layout: xq (1 MB) | agg (16 MB)
  float4* xq = (float4*)d_ws;
  float* agg = (float*)((char*)d_ws + 6291456);
  float* out = (float*)d_out;
  // Folded-weight scratch (4.1 KB) at the START of d_out: point_kernel reads it, then
  // conv2 overwrites every element of d_out (stream-serialized) -> race-free.
  float* wf = (float*)d_out;

  prep_kernel<<<257, 256, 0, stream>>>(x, xq, Wk, Wv, Ws, bnk, bnv, bns, wf);
  point_kernel<<<16384, 256, 0, stream>>>(xq, wf, agg);
  conv2_kernel<<<512, 256, 0, stream>>>(agg, W2, b2, bnc2, out);
}